// Round 1
// baseline (2217.240 us; speedup 1.0000x reference)
//
#include <hip/hip_runtime.h>
#include <math.h>

// ---------------------------------------------------------------------------
// TransformerBlock: LN -> QKV -> MHA -> Wo(+resid) -> LN -> top1-MoE(+resid)
// Round 1: all-fp32 (argmax top-1 routing is precision-critical: bf16 anywhere
// pre-gate flips expert assignments vs the fp32 numpy reference -> O(1) errors).
// ---------------------------------------------------------------------------

constexpr int NB = 4, NS = 1024, NHID = 1024, NHEAD = 16, HD = 64, NE = 8, NF = 4096;
constexpr int NT = NB * NS;          // 4096 tokens
constexpr float LN_EPS = 1e-5f;

// ---------------- LayerNorm: one block (256 thr) per token row --------------
__global__ __launch_bounds__(256)
void ln_kernel(const float* __restrict__ x, const float* __restrict__ g,
               const float* __restrict__ b, float* __restrict__ y)
{
    const int t = blockIdx.x, tid = threadIdx.x;
    const float4 xv = ((const float4*)(x + (size_t)t * NHID))[tid];
    float s  = xv.x + xv.y + xv.z + xv.w;
    float sq = xv.x*xv.x + xv.y*xv.y + xv.z*xv.z + xv.w*xv.w;
    for (int off = 32; off > 0; off >>= 1) {
        s  += __shfl_down(s, off);
        sq += __shfl_down(sq, off);
    }
    __shared__ float ws_[4], wsq_[4], stats[2];
    const int wid = tid >> 6, lane = tid & 63;
    if (lane == 0) { ws_[wid] = s; wsq_[wid] = sq; }
    __syncthreads();
    if (tid == 0) {
        const float ts = ws_[0] + ws_[1] + ws_[2] + ws_[3];
        const float tq = wsq_[0] + wsq_[1] + wsq_[2] + wsq_[3];
        const float mu = ts * (1.0f / NHID);
        const float var = tq * (1.0f / NHID) - mu * mu;
        stats[0] = mu; stats[1] = rsqrtf(var + LN_EPS);
    }
    __syncthreads();
    const float mu = stats[0], rs = stats[1];
    const float4 gv = ((const float4*)g)[tid];
    const float4 bv = ((const float4*)b)[tid];
    float4 ov;
    ov.x = (xv.x - mu) * rs * gv.x + bv.x;
    ov.y = (xv.y - mu) * rs * gv.y + bv.y;
    ov.z = (xv.z - mu) * rs * gv.z + bv.z;
    ov.w = (xv.w - mu) * rs * gv.w + bv.w;
    ((float4*)(y + (size_t)t * NHID))[tid] = ov;
}

// ---------------- Generic fp32 SGEMM: C = A @ W + bias (+resid)(+relu) ------
// TILE x TILE block tile, 256 threads, (TILE/64*4)^2 outputs/thread, BK=16.
// EXPERT: rows gathered via token list (top-1 MoE grouped dispatch), M=Mmax,
//         Meff=counts[z], W/bias are per-expert slices.
// QKV3:   blockIdx.z in {0,1,2} selects (W0,b0)/(W1,b1)/(W2,b2), C += z*M*N.
template<int TILE, bool EXPERT, bool RELU, bool RESID, bool QKV3>
__global__ __launch_bounds__(256)
void gemm_kernel(const float* __restrict__ A,
                 const float* __restrict__ W0, const float* __restrict__ W1,
                 const float* __restrict__ W2,
                 const float* __restrict__ bias0, const float* __restrict__ bias1,
                 const float* __restrict__ bias2,
                 const float* __restrict__ resid, float* __restrict__ C,
                 int M, int N, int K,
                 const int* __restrict__ rows, const int* __restrict__ counts)
{
    constexpr int RF = TILE / 64;            // 1 (64-tile) or 2 (128-tile)
    __shared__ float As[16][TILE];           // A tile, transposed (k-major)
    __shared__ float Bs[16][TILE];

    const int z    = (EXPERT || QKV3) ? blockIdx.z : 0;
    const int Meff = EXPERT ? counts[z] : M;
    const int m0   = blockIdx.y * TILE;
    if (EXPERT && m0 >= Meff) return;        // empty / out-of-range expert tile
    const int n0   = blockIdx.x * TILE;

    const float* Wp = W0; const float* bp = bias0;
    if (QKV3) { if (z == 1) { Wp = W1; bp = bias1; } else if (z == 2) { Wp = W2; bp = bias2; } }
    if (EXPERT) { Wp = W0 + (size_t)z * K * N; bp = bias0 + (size_t)z * N; }
    float* Cp = C;
    if (QKV3) Cp = C + (size_t)z * M * N;
    const int* rl = EXPERT ? rows + (size_t)z * M : nullptr;

    const int tid = threadIdx.x;
    const int tr = tid >> 4, tc = tid & 15;
    const int kqA = (tid & 3) * 4;

    // per-thread staging descriptors (row gather resolved once)
    int lrA[RF]; const float* pA[RF];
    int kkB[RF], jB[RF];
    #pragma unroll
    for (int i = 0; i < RF; ++i) {
        const int c = tid + i * 256;
        lrA[i] = c >> 2;
        const int m = m0 + lrA[i];
        int gr = -1;
        if (m < Meff) gr = EXPERT ? rl[m] : m;
        pA[i] = (gr >= 0) ? A + (size_t)gr * K + kqA : nullptr;
        kkB[i] = c / (TILE / 4);
        jB[i]  = (c % (TILE / 4)) * 4;
    }

    float acc[4 * RF][4 * RF] = {};

    for (int k0 = 0; k0 < K; k0 += 16) {
        float4 a[RF], bb[RF];
        #pragma unroll
        for (int i = 0; i < RF; ++i)
            a[i] = pA[i] ? *(const float4*)(pA[i] + k0) : make_float4(0.f, 0.f, 0.f, 0.f);
        #pragma unroll
        for (int i = 0; i < RF; ++i)
            bb[i] = *(const float4*)(Wp + (size_t)(k0 + kkB[i]) * N + n0 + jB[i]);
        __syncthreads();
        #pragma unroll
        for (int i = 0; i < RF; ++i) {
            As[kqA + 0][lrA[i]] = a[i].x;
            As[kqA + 1][lrA[i]] = a[i].y;
            As[kqA + 2][lrA[i]] = a[i].z;
            As[kqA + 3][lrA[i]] = a[i].w;
            *(float4*)&Bs[kkB[i]][jB[i]] = bb[i];
        }
        __syncthreads();
        #pragma unroll
        for (int kk = 0; kk < 16; ++kk) {
            float av[4 * RF], bv[4 * RF];
            #pragma unroll
            for (int h = 0; h < RF; ++h) {
                *(float4*)&av[4 * h] = *(const float4*)&As[kk][64 * h + tr * 4];
                *(float4*)&bv[4 * h] = *(const float4*)&Bs[kk][64 * h + tc * 4];
            }
            #pragma unroll
            for (int i = 0; i < 4 * RF; ++i)
                #pragma unroll
                for (int j = 0; j < 4 * RF; ++j)
                    acc[i][j] += av[i] * bv[j];
        }
    }

    // epilogue: bias (+resid)(+relu), scatter by gathered row
    #pragma unroll
    for (int i = 0; i < 4 * RF; ++i) {
        const int lr = 64 * (i >> 2) + tr * 4 + (i & 3);
        const int m = m0 + lr;
        if (m >= Meff) continue;
        const int gr = EXPERT ? rl[m] : m;
        const size_t ro = (size_t)gr * N;
        #pragma unroll
        for (int jh = 0; jh < RF; ++jh) {
            const int col = n0 + 64 * jh + tc * 4;
            float4 vv;
            vv.x = acc[i][4 * jh + 0] + bp[col + 0];
            vv.y = acc[i][4 * jh + 1] + bp[col + 1];
            vv.z = acc[i][4 * jh + 2] + bp[col + 2];
            vv.w = acc[i][4 * jh + 3] + bp[col + 3];
            if (RESID) {
                const float4 rv = *(const float4*)&resid[ro + col];
                vv.x += rv.x; vv.y += rv.y; vv.z += rv.z; vv.w += rv.w;
            }
            if (RELU) {
                vv.x = fmaxf(vv.x, 0.f); vv.y = fmaxf(vv.y, 0.f);
                vv.z = fmaxf(vv.z, 0.f); vv.w = fmaxf(vv.w, 0.f);
            }
            *(float4*)&Cp[ro + col] = vv;
        }
    }
}

// ---------------- Flash-style fp32 attention --------------------------------
// grid (S/64, NH, B), 256 thr. 64-row Q tile, online softmax over 16 K-tiles.
// K and V stored in LDS as XOR-swizzled float4 slots -> conflict-free b128.
__device__ __forceinline__ int kvslot(int j, int s) {
    return s ^ (j >> 2) ^ ((j & 3) << 2);   // bijective in s for fixed j
}

__global__ __launch_bounds__(256)
void attn_kernel(const float* __restrict__ q, const float* __restrict__ k,
                 const float* __restrict__ v, float* __restrict__ o)
{
    __shared__ float Qs[64][68];     // pad 68: float4-aligned, 2-way max
    __shared__ float Vsw[64 * 64];   // swizzled V
    __shared__ float KP[64 * 64];    // swizzled K, then P (plain [i][j])

    const int qt = blockIdx.x, h = blockIdx.y, b = blockIdx.z;
    const int tid = threadIdx.x;
    const int tr = tid >> 4, tc = tid & 15;
    const size_t base = ((size_t)b * NS) * NHID + (size_t)h * HD;

    for (int c = tid; c < 64 * 16; c += 256) {
        const int i = c >> 4, d4 = (c & 15) << 2;
        const float4 qv = *(const float4*)&q[base + (size_t)(qt * 64 + i) * NHID + d4];
        Qs[i][d4 + 0] = qv.x * 0.125f;   // fold 1/sqrt(D)
        Qs[i][d4 + 1] = qv.y * 0.125f;
        Qs[i][d4 + 2] = qv.z * 0.125f;
        Qs[i][d4 + 3] = qv.w * 0.125f;
    }

    float m_run[4], l_run[4], o_acc[4][4];
    #pragma unroll
    for (int i = 0; i < 4; ++i) {
        m_run[i] = -1e30f; l_run[i] = 0.f;
        #pragma unroll
        for (int d = 0; d < 4; ++d) o_acc[i][d] = 0.f;
    }

    for (int kt = 0; kt < NS / 64; ++kt) {
        __syncthreads();   // prev PV reads done (also covers Qs on first iter via next barrier)
        for (int c = tid; c < 64 * 16; c += 256) {
            const int j = c >> 4, d4 = (c & 15) << 2;
            const int ss = kvslot(j, d4 >> 2);
            const float4 kv = *(const float4*)&k[base + (size_t)(kt * 64 + j) * NHID + d4];
            *(float4*)&KP[j * 64 + ss * 4] = kv;
            const float4 vv = *(const float4*)&v[base + (size_t)(kt * 64 + j) * NHID + d4];
            *(float4*)&Vsw[j * 64 + ss * 4] = vv;
        }
        __syncthreads();

        // S tile: rows tr*4+ii, cols tc*4+jj
        float sc[4][4] = {};
        #pragma unroll 2
        for (int d4 = 0; d4 < 64; d4 += 4) {
            float4 qv[4], kv[4];
            #pragma unroll
            for (int ii = 0; ii < 4; ++ii)
                qv[ii] = *(const float4*)&Qs[tr * 4 + ii][d4];
            #pragma unroll
            for (int jj = 0; jj < 4; ++jj) {
                const int j = tc * 4 + jj;
                kv[jj] = *(const float4*)&KP[j * 64 + kvslot(j, d4 >> 2) * 4];
            }
            #pragma unroll
            for (int ii = 0; ii < 4; ++ii)
                #pragma unroll
                for (int jj = 0; jj < 4; ++jj)
                    sc[ii][jj] += qv[ii].x * kv[jj].x + qv[ii].y * kv[jj].y
                                + qv[ii].z * kv[jj].z + qv[ii].w * kv[jj].w;
        }

        // online softmax; 16 lanes (same tr) own a row, xor-reduce over tc
        float p[4][4], alpha[4];
        #pragma unroll
        for (int ii = 0; ii < 4; ++ii) {
            float tm = fmaxf(fmaxf(sc[ii][0], sc[ii][1]), fmaxf(sc[ii][2], sc[ii][3]));
            for (int msk = 1; msk < 16; msk <<= 1) tm = fmaxf(tm, __shfl_xor(tm, msk));
            const float newm = fmaxf(m_run[ii], tm);
            alpha[ii] = __expf(m_run[ii] - newm);
            float ps = 0.f;
            #pragma unroll
            for (int jj = 0; jj < 4; ++jj) { p[ii][jj] = __expf(sc[ii][jj] - newm); ps += p[ii][jj]; }
            for (int msk = 1; msk < 16; msk <<= 1) ps += __shfl_xor(ps, msk);
            l_run[ii] = l_run[ii] * alpha[ii] + ps;
            m_run[ii] = newm;
        }
        __syncthreads();   // all K reads done -> safe to overwrite KP with P
        #pragma unroll
        for (int ii = 0; ii < 4; ++ii)
            #pragma unroll
            for (int jj = 0; jj < 4; ++jj)
                KP[(tr * 4 + ii) * 64 + tc * 4 + jj] = p[ii][jj];
        __syncthreads();

        // PV: O[i][4tc..+3] += sum_j P[i][j] * V[j][4tc..+3]
        #pragma unroll
        for (int ii = 0; ii < 4; ++ii)
            #pragma unroll
            for (int dd = 0; dd < 4; ++dd)
                o_acc[ii][dd] *= alpha[ii];
        #pragma unroll 4
        for (int j = 0; j < 64; ++j) {
            const float4 vv = *(const float4*)&Vsw[j * 64 + kvslot(j, tc) * 4];
            float pr[4];
            #pragma unroll
            for (int ii = 0; ii < 4; ++ii) pr[ii] = KP[(tr * 4 + ii) * 64 + j];
            #pragma unroll
            for (int ii = 0; ii < 4; ++ii) {
                o_acc[ii][0] += pr[ii] * vv.x;
                o_acc[ii][1] += pr[ii] * vv.y;
                o_acc[ii][2] += pr[ii] * vv.z;
                o_acc[ii][3] += pr[ii] * vv.w;
            }
        }
    }

    #pragma unroll
    for (int ii = 0; ii < 4; ++ii) {
        const float inv = 1.f / l_run[ii];
        float4 ov;
        ov.x = o_acc[ii][0] * inv; ov.y = o_acc[ii][1] * inv;
        ov.z = o_acc[ii][2] * inv; ov.w = o_acc[ii][3] * inv;
        *(float4*)&o[base + (size_t)(qt * 64 + tr * 4 + ii) * NHID + tc * 4] = ov;
    }
}

// ---------------- Gate: logits fp32, argmax (first-max ties), token scatter -
__global__ __launch_bounds__(64)
void gate_kernel(const float* __restrict__ hn2, const float* __restrict__ gw,
                 const float* __restrict__ gb, int* __restrict__ counts,
                 int* __restrict__ tok)
{
    const int t = blockIdx.x, lane = threadIdx.x;
    const float* row = hn2 + (size_t)t * NHID;
    float acc[NE] = {};
    for (int hh = lane; hh < NHID; hh += 64) {
        const float xv = row[hh];
        const float4 g0 = ((const float4*)(gw + (size_t)hh * NE))[0];
        const float4 g1 = ((const float4*)(gw + (size_t)hh * NE))[1];
        acc[0] += xv * g0.x; acc[1] += xv * g0.y; acc[2] += xv * g0.z; acc[3] += xv * g0.w;
        acc[4] += xv * g1.x; acc[5] += xv * g1.y; acc[6] += xv * g1.z; acc[7] += xv * g1.w;
    }
    #pragma unroll
    for (int e = 0; e < NE; ++e)
        for (int off = 32; off > 0; off >>= 1)
            acc[e] += __shfl_down(acc[e], off);
    if (lane == 0) {
        float best = -1e30f; int bi = 0;
        #pragma unroll
        for (int e = 0; e < NE; ++e) {
            const float lv = acc[e] + gb[e];
            if (lv > best) { best = lv; bi = e; }   // strict >: first-max wins (jnp.argmax)
        }
        const int pos = atomicAdd(&counts[bi], 1);
        tok[(size_t)bi * NT + pos] = t;
    }
}

// ---------------------------------------------------------------------------
extern "C" void kernel_launch(void* const* d_in, const int* in_sizes, int n_in,
                              void* d_out, int out_size, void* d_ws, size_t ws_size,
                              hipStream_t stream)
{
    (void)in_sizes; (void)n_in; (void)out_size; (void)ws_size;
    const float* x      = (const float*)d_in[0];
    const float* ln1_g  = (const float*)d_in[1];
    const float* ln1_b  = (const float*)d_in[2];
    const float* ln2_g  = (const float*)d_in[3];
    const float* ln2_b  = (const float*)d_in[4];
    const float* wq     = (const float*)d_in[5];
    const float* bq     = (const float*)d_in[6];
    const float* wk     = (const float*)d_in[7];
    const float* bk     = (const float*)d_in[8];
    const float* wv     = (const float*)d_in[9];
    const float* bv     = (const float*)d_in[10];
    const float* wo     = (const float*)d_in[11];
    const float* bo     = (const float*)d_in[12];
    const float* gate_w = (const float*)d_in[13];
    const float* gate_b = (const float*)d_in[14];
    const float* w1     = (const float*)d_in[15];
    const float* b1     = (const float*)d_in[16];
    const float* w2     = (const float*)d_in[17];
    const float* b2     = (const float*)d_in[18];
    float* out = (float*)d_out;

    // workspace layout (floats), with buffer aliasing:
    //   buf0: hn  -> attn out o
    //   buf1: q   -> x2 (post-attn residual)
    //   buf2: k   -> hn2
    //   buf3: v
    //   mid:  [NT, NF]
    const size_t TH = (size_t)NT * NHID;                 // 4M floats
    float* ws   = (float*)d_ws;
    float* hn   = ws;                 // == o
    float* qb   = ws + TH;            // == x2  (q,k,v contiguous for QKV3)
    float* kb   = ws + 2 * TH;        // == hn2
    float* vb   = ws + 3 * TH;
    float* mid  = ws + 4 * TH;        // NT*NF = 16M floats
    int*   tok  = (int*)(ws + 4 * TH + (size_t)NT * NF);
    int*   cnts = tok + (size_t)NE * NT;

    ln_kernel<<<NT, 256, 0, stream>>>(x, ln1_g, ln1_b, hn);

    // QKV fused over blockIdx.z (768 blocks -> 3 blocks/CU)
    {
        dim3 g(NHID / 128, NT / 128, 3);
        gemm_kernel<128, false, false, false, true><<<g, 256, 0, stream>>>(
            hn, wq, wk, wv, bq, bk, bv, nullptr, qb, NT, NHID, NHID, nullptr, nullptr);
    }

    {
        dim3 g(NS / 64, NHEAD, NB);
        attn_kernel<<<g, 256, 0, stream>>>(qb, kb, vb, hn);   // o -> buf0
    }

    // x2 = x + o @ wo + bo   (64-tile: 1024 blocks for occupancy)
    {
        dim3 g(NHID / 64, NT / 64, 1);
        gemm_kernel<64, false, false, true, false><<<g, 256, 0, stream>>>(
            hn, wo, nullptr, nullptr, bo, nullptr, nullptr, x, qb, NT, NHID, NHID, nullptr, nullptr);
    }

    ln_kernel<<<NT, 256, 0, stream>>>(qb, ln2_g, ln2_b, kb);  // hn2 -> buf2

    hipMemsetAsync(cnts, 0, NE * sizeof(int), stream);
    gate_kernel<<<NT, 64, 0, stream>>>(kb, gate_w, gate_b, cnts, tok);

    // expert GEMM1: mid[t,f] = relu(hn2[t] @ w1[e] + b1[e]), gathered rows
    {
        dim3 g(NF / 128, NT / 128, NE);
        gemm_kernel<128, true, true, false, false><<<g, 256, 0, stream>>>(
            kb, w1, nullptr, nullptr, b1, nullptr, nullptr, nullptr, mid, NT, NF, NHID, tok, cnts);
    }
    // expert GEMM2: out[t] = x2[t] + mid[t] @ w2[e] + b2[e]
    {
        dim3 g(NHID / 64, NT / 64, NE);
        gemm_kernel<64, true, false, true, false><<<g, 256, 0, stream>>>(
            mid, w2, nullptr, nullptr, b2, nullptr, nullptr, qb, out, NT, NHID, NF, tok, cnts);
    }
}

// Round 2
// 1572.894 us; speedup vs baseline: 1.4097x; 1.4097x over previous
//
#include <hip/hip_runtime.h>
#include <math.h>

// ---------------------------------------------------------------------------
// TransformerBlock: LN -> QKV -> MHA -> Wo(+resid) -> LN -> top1-MoE(+resid)
// R2: pre-gate path fp32 (argmax routing precision-critical); post-gate MoE
// expert GEMMs in bf16 MFMA (m97-style 128-tile, global_load_lds, 16x16x32).
// ---------------------------------------------------------------------------

constexpr int NB = 4, NS = 1024, NHID = 1024, NHEAD = 16, HD = 64, NE = 8, NF = 4096;
constexpr int NT = NB * NS;          // 4096 tokens
constexpr float LN_EPS = 1e-5f;
constexpr size_t MiB = 1048576;

using bf16x8 = __attribute__((ext_vector_type(8))) short;
using f32x4  = __attribute__((ext_vector_type(4))) float;

__device__ __forceinline__ unsigned short f2bf(float x) {
    unsigned u = __float_as_uint(x);
    return (unsigned short)((u + 0x7fffu + ((u >> 16) & 1u)) >> 16);   // RNE
}

__device__ __forceinline__ void gload_lds16(const void* g, void* l) {
    __builtin_amdgcn_global_load_lds(
        (const __attribute__((address_space(1))) void*)g,
        (__attribute__((address_space(3))) void*)l, 16, 0, 0);
}

// ---------------- LayerNorm: one block (256 thr) per token row --------------
template<bool BF16OUT>
__global__ __launch_bounds__(256)
void ln_kernel(const float* __restrict__ x, const float* __restrict__ g,
               const float* __restrict__ b, float* __restrict__ y,
               unsigned short* __restrict__ ybf)
{
    const int t = blockIdx.x, tid = threadIdx.x;
    const float4 xv = ((const float4*)(x + (size_t)t * NHID))[tid];
    float s  = xv.x + xv.y + xv.z + xv.w;
    float sq = xv.x*xv.x + xv.y*xv.y + xv.z*xv.z + xv.w*xv.w;
    for (int off = 32; off > 0; off >>= 1) {
        s  += __shfl_down(s, off);
        sq += __shfl_down(sq, off);
    }
    __shared__ float ws_[4], wsq_[4], stats[2];
    const int wid = tid >> 6, lane = tid & 63;
    if (lane == 0) { ws_[wid] = s; wsq_[wid] = sq; }
    __syncthreads();
    if (tid == 0) {
        const float ts = ws_[0] + ws_[1] + ws_[2] + ws_[3];
        const float tq = wsq_[0] + wsq_[1] + wsq_[2] + wsq_[3];
        const float mu = ts * (1.0f / NHID);
        const float var = tq * (1.0f / NHID) - mu * mu;
        stats[0] = mu; stats[1] = rsqrtf(var + LN_EPS);
    }
    __syncthreads();
    const float mu = stats[0], rs = stats[1];
    const float4 gv = ((const float4*)g)[tid];
    const float4 bv = ((const float4*)b)[tid];
    float4 ov;
    ov.x = (xv.x - mu) * rs * gv.x + bv.x;
    ov.y = (xv.y - mu) * rs * gv.y + bv.y;
    ov.z = (xv.z - mu) * rs * gv.z + bv.z;
    ov.w = (xv.w - mu) * rs * gv.w + bv.w;
    ((float4*)(y + (size_t)t * NHID))[tid] = ov;
    if (BF16OUT) {
        unsigned long long p = (unsigned long long)f2bf(ov.x)
                             | ((unsigned long long)f2bf(ov.y) << 16)
                             | ((unsigned long long)f2bf(ov.z) << 32)
                             | ((unsigned long long)f2bf(ov.w) << 48);
        ((unsigned long long*)(ybf + (size_t)t * NHID))[tid] = p;
    }
}

// ---------------- fp32 SGEMM (pre-gate path): C = A @ W + bias (+resid) -----
// TILE x TILE block tile, 256 threads, BK=16.
// QKV3: blockIdx.z in {0,1,2} selects (W0,b0,C0)/(W1,b1,C1)/(W2,b2,C2).
template<int TILE, bool RESID, bool QKV3>
__global__ __launch_bounds__(256)
void gemm_kernel(const float* __restrict__ A,
                 const float* __restrict__ W0, const float* __restrict__ W1,
                 const float* __restrict__ W2,
                 const float* __restrict__ bias0, const float* __restrict__ bias1,
                 const float* __restrict__ bias2,
                 const float* __restrict__ resid,
                 float* __restrict__ C0, float* __restrict__ C1, float* __restrict__ C2,
                 int M, int N, int K)
{
    constexpr int RF = TILE / 64;            // 1 (64-tile) or 2 (128-tile)
    __shared__ float As[16][TILE];           // A tile, transposed (k-major)
    __shared__ float Bs[16][TILE];

    const int z  = QKV3 ? blockIdx.z : 0;
    const int m0 = blockIdx.y * TILE;
    const int n0 = blockIdx.x * TILE;

    const float* Wp = W0; const float* bp = bias0; float* Cp = C0;
    if (QKV3) {
        if (z == 1)      { Wp = W1; bp = bias1; Cp = C1; }
        else if (z == 2) { Wp = W2; bp = bias2; Cp = C2; }
    }

    const int tid = threadIdx.x;
    const int tr = tid >> 4, tc = tid & 15;
    const int kqA = (tid & 3) * 4;

    int lrA[RF]; const float* pA[RF];
    int kkB[RF], jB[RF];
    #pragma unroll
    for (int i = 0; i < RF; ++i) {
        const int c = tid + i * 256;
        lrA[i] = c >> 2;
        pA[i]  = A + (size_t)(m0 + lrA[i]) * K + kqA;
        kkB[i] = c / (TILE / 4);
        jB[i]  = (c % (TILE / 4)) * 4;
    }

    float acc[4 * RF][4 * RF] = {};

    for (int k0 = 0; k0 < K; k0 += 16) {
        float4 a[RF], bb[RF];
        #pragma unroll
        for (int i = 0; i < RF; ++i)
            a[i] = *(const float4*)(pA[i] + k0);
        #pragma unroll
        for (int i = 0; i < RF; ++i)
            bb[i] = *(const float4*)(Wp + (size_t)(k0 + kkB[i]) * N + n0 + jB[i]);
        __syncthreads();
        #pragma unroll
        for (int i = 0; i < RF; ++i) {
            As[kqA + 0][lrA[i]] = a[i].x;
            As[kqA + 1][lrA[i]] = a[i].y;
            As[kqA + 2][lrA[i]] = a[i].z;
            As[kqA + 3][lrA[i]] = a[i].w;
            *(float4*)&Bs[kkB[i]][jB[i]] = bb[i];
        }
        __syncthreads();
        #pragma unroll
        for (int kk = 0; kk < 16; ++kk) {
            float av[4 * RF], bv[4 * RF];
            #pragma unroll
            for (int h = 0; h < RF; ++h) {
                *(float4*)&av[4 * h] = *(const float4*)&As[kk][64 * h + tr * 4];
                *(float4*)&bv[4 * h] = *(const float4*)&Bs[kk][64 * h + tc * 4];
            }
            #pragma unroll
            for (int i = 0; i < 4 * RF; ++i)
                #pragma unroll
                for (int j = 0; j < 4 * RF; ++j)
                    acc[i][j] += av[i] * bv[j];
        }
    }

    #pragma unroll
    for (int i = 0; i < 4 * RF; ++i) {
        const int lr = 64 * (i >> 2) + tr * 4 + (i & 3);
        const size_t ro = (size_t)(m0 + lr) * N;
        #pragma unroll
        for (int jh = 0; jh < RF; ++jh) {
            const int col = n0 + 64 * jh + tc * 4;
            float4 vv;
            vv.x = acc[i][4 * jh + 0] + bp[col + 0];
            vv.y = acc[i][4 * jh + 1] + bp[col + 1];
            vv.z = acc[i][4 * jh + 2] + bp[col + 2];
            vv.w = acc[i][4 * jh + 3] + bp[col + 3];
            if (RESID) {
                const float4 rv = *(const float4*)&resid[ro + col];
                vv.x += rv.x; vv.y += rv.y; vv.z += rv.z; vv.w += rv.w;
            }
            *(float4*)&Cp[ro + col] = vv;
        }
    }
}

// ---------------- Flash-style fp32 attention (unchanged from R1) ------------
__device__ __forceinline__ int kvslot(int j, int s) {
    return s ^ (j >> 2) ^ ((j & 3) << 2);
}

__global__ __launch_bounds__(256)
void attn_kernel(const float* __restrict__ q, const float* __restrict__ k,
                 const float* __restrict__ v, float* __restrict__ o)
{
    __shared__ float Qs[64][68];
    __shared__ float Vsw[64 * 64];
    __shared__ float KP[64 * 64];

    const int qt = blockIdx.x, h = blockIdx.y, b = blockIdx.z;
    const int tid = threadIdx.x;
    const int tr = tid >> 4, tc = tid & 15;
    const size_t base = ((size_t)b * NS) * NHID + (size_t)h * HD;

    for (int c = tid; c < 64 * 16; c += 256) {
        const int i = c >> 4, d4 = (c & 15) << 2;
        const float4 qv = *(const float4*)&q[base + (size_t)(qt * 64 + i) * NHID + d4];
        Qs[i][d4 + 0] = qv.x * 0.125f;
        Qs[i][d4 + 1] = qv.y * 0.125f;
        Qs[i][d4 + 2] = qv.z * 0.125f;
        Qs[i][d4 + 3] = qv.w * 0.125f;
    }

    float m_run[4], l_run[4], o_acc[4][4];
    #pragma unroll
    for (int i = 0; i < 4; ++i) {
        m_run[i] = -1e30f; l_run[i] = 0.f;
        #pragma unroll
        for (int d = 0; d < 4; ++d) o_acc[i][d] = 0.f;
    }

    for (int kt = 0; kt < NS / 64; ++kt) {
        __syncthreads();
        for (int c = tid; c < 64 * 16; c += 256) {
            const int j = c >> 4, d4 = (c & 15) << 2;
            const int ss = kvslot(j, d4 >> 2);
            const float4 kv = *(const float4*)&k[base + (size_t)(kt * 64 + j) * NHID + d4];
            *(float4*)&KP[j * 64 + ss * 4] = kv;
            const float4 vv = *(const float4*)&v[base + (size_t)(kt * 64 + j) * NHID + d4];
            *(float4*)&Vsw[j * 64 + ss * 4] = vv;
        }
        __syncthreads();

        float sc[4][4] = {};
        #pragma unroll 2
        for (int d4 = 0; d4 < 64; d4 += 4) {
            float4 qv[4], kv[4];
            #pragma unroll
            for (int ii = 0; ii < 4; ++ii)
                qv[ii] = *(const float4*)&Qs[tr * 4 + ii][d4];
            #pragma unroll
            for (int jj = 0; jj < 4; ++jj) {
                const int j = tc * 4 + jj;
                kv[jj] = *(const float4*)&KP[j * 64 + kvslot(j, d4 >> 2) * 4];
            }
            #pragma unroll
            for (int ii = 0; ii < 4; ++ii)
                #pragma unroll
                for (int jj = 0; jj < 4; ++jj)
                    sc[ii][jj] += qv[ii].x * kv[jj].x + qv[ii].y * kv[jj].y
                                + qv[ii].z * kv[jj].z + qv[ii].w * kv[jj].w;
        }

        float p[4][4], alpha[4];
        #pragma unroll
        for (int ii = 0; ii < 4; ++ii) {
            float tm = fmaxf(fmaxf(sc[ii][0], sc[ii][1]), fmaxf(sc[ii][2], sc[ii][3]));
            for (int msk = 1; msk < 16; msk <<= 1) tm = fmaxf(tm, __shfl_xor(tm, msk));
            const float newm = fmaxf(m_run[ii], tm);
            alpha[ii] = __expf(m_run[ii] - newm);
            float ps = 0.f;
            #pragma unroll
            for (int jj = 0; jj < 4; ++jj) { p[ii][jj] = __expf(sc[ii][jj] - newm); ps += p[ii][jj]; }
            for (int msk = 1; msk < 16; msk <<= 1) ps += __shfl_xor(ps, msk);
            l_run[ii] = l_run[ii] * alpha[ii] + ps;
            m_run[ii] = newm;
        }
        __syncthreads();
        #pragma unroll
        for (int ii = 0; ii < 4; ++ii)
            #pragma unroll
            for (int jj = 0; jj < 4; ++jj)
                KP[(tr * 4 + ii) * 64 + tc * 4 + jj] = p[ii][jj];
        __syncthreads();

        #pragma unroll
        for (int ii = 0; ii < 4; ++ii)
            #pragma unroll
            for (int dd = 0; dd < 4; ++dd)
                o_acc[ii][dd] *= alpha[ii];
        #pragma unroll 4
        for (int j = 0; j < 64; ++j) {
            const float4 vv = *(const float4*)&Vsw[j * 64 + kvslot(j, tc) * 4];
            float pr[4];
            #pragma unroll
            for (int ii = 0; ii < 4; ++ii) pr[ii] = KP[(tr * 4 + ii) * 64 + j];
            #pragma unroll
            for (int ii = 0; ii < 4; ++ii) {
                o_acc[ii][0] += pr[ii] * vv.x;
                o_acc[ii][1] += pr[ii] * vv.y;
                o_acc[ii][2] += pr[ii] * vv.z;
                o_acc[ii][3] += pr[ii] * vv.w;
            }
        }
    }

    #pragma unroll
    for (int ii = 0; ii < 4; ++ii) {
        const float inv = 1.f / l_run[ii];
        float4 ov;
        ov.x = o_acc[ii][0] * inv; ov.y = o_acc[ii][1] * inv;
        ov.z = o_acc[ii][2] * inv; ov.w = o_acc[ii][3] * inv;
        *(float4*)&o[base + (size_t)(qt * 64 + tr * 4 + ii) * NHID + tc * 4] = ov;
    }
}

// ---------------- Gate: fp32 logits, argmax (first-max), token scatter ------
__global__ __launch_bounds__(64)
void gate_kernel(const float* __restrict__ hn2, const float* __restrict__ gw,
                 const float* __restrict__ gb, int* __restrict__ counts,
                 int* __restrict__ tok)
{
    const int t = blockIdx.x, lane = threadIdx.x;
    const float* row = hn2 + (size_t)t * NHID;
    float acc[NE] = {};
    for (int hh = lane; hh < NHID; hh += 64) {
        const float xv = row[hh];
        const float4 g0 = ((const float4*)(gw + (size_t)hh * NE))[0];
        const float4 g1 = ((const float4*)(gw + (size_t)hh * NE))[1];
        acc[0] += xv * g0.x; acc[1] += xv * g0.y; acc[2] += xv * g0.z; acc[3] += xv * g0.w;
        acc[4] += xv * g1.x; acc[5] += xv * g1.y; acc[6] += xv * g1.z; acc[7] += xv * g1.w;
    }
    #pragma unroll
    for (int e = 0; e < NE; ++e)
        for (int off = 32; off > 0; off >>= 1)
            acc[e] += __shfl_down(acc[e], off);
    if (lane == 0) {
        float best = -1e30f; int bi = 0;
        #pragma unroll
        for (int e = 0; e < NE; ++e) {
            const float lv = acc[e] + gb[e];
            if (lv > best) { best = lv; bi = e; }
        }
        const int pos = atomicAdd(&counts[bi], 1);
        tok[(size_t)bi * NT + pos] = t;
    }
}

// ---------------- Pack weights: fp32 [E][K][N] -> bf16 [E][K/8][N][8] -------
__global__ __launch_bounds__(256)
void pack_w(const float* __restrict__ w, unsigned short* __restrict__ out,
            int K, int N)
{
    const int e = blockIdx.z, k8 = blockIdx.y;
    const int col = blockIdx.x * 256 + threadIdx.x;
    const float* src = w + ((size_t)e * K + (size_t)k8 * 8) * N + col;
    unsigned short tmp[8] __attribute__((aligned(16)));
    #pragma unroll
    for (int j = 0; j < 8; ++j) tmp[j] = f2bf(src[(size_t)j * N]);
    *(f32x4*)(out + (((size_t)e * (K / 8) + k8) * N + col) * 8) = *(const f32x4*)tmp;
}

// ---------------- MoE expert GEMM, bf16 MFMA (m97-style) --------------------
// C[tok[m]] = [relu](gather(A)[m] @ Bpacked[e] + bias[e]) [+ resid]
// BM=128, BK=32, BN template. 256 thr = 4 waves in 2x2. LDS chunk layouts:
//   As: [k8=4][row=128][8] bf16 (chunk id = q*128+row, 16B each)
//   Bs: [k8=4][n=BN][8]   bf16 (chunk id = q*BN+n)
// Both a_frag/b_frag ds_read_b128 are baseline-conflict contiguous reads.
template<int BN, bool BF16OUT>
__global__ __launch_bounds__(256, 2)
void moe_mfma(const unsigned short* __restrict__ A,   // bf16 [NT][K]
              const unsigned short* __restrict__ Bp,  // bf16 packed [E][K/8][N][8]
              const float* __restrict__ bias,         // [E][N]
              const float* __restrict__ resid,        // [NT][N] or null
              void* __restrict__ Cout,                // bf16 or fp32 [NT][N]
              int N, int K,
              const int* __restrict__ rows, const int* __restrict__ counts)
{
    constexpr int NI = BN / 32;                 // n-tiles per wave
    constexpr int NBCH = (4 * BN) / 256;        // B chunks per thread
    __shared__ __attribute__((aligned(16))) unsigned short As[4 * 128 * 8];
    __shared__ __attribute__((aligned(16))) unsigned short Bs[4 * BN * 8];

    const int e = blockIdx.z;
    const int Meff = counts[e];
    const int m0 = blockIdx.y * 128;
    if (m0 >= Meff) return;
    const int n0 = blockIdx.x * BN;
    const int* rl = rows + (size_t)e * NT;

    const int tid  = threadIdx.x;
    const int lane = tid & 63, wid = tid >> 6;
    const int quad = lane >> 4, l16 = lane & 15;
    const int wm = (wid >> 1) * 64;             // wave M origin in tile
    const int wn = (wid & 1) * (BN / 2);        // wave N origin in tile

    // staging descriptors: LDS dest = wave-uniform base + lane*16 (chunk = c)
    const unsigned short* gA[2]; void* lA[2];
    #pragma unroll
    for (int i = 0; i < 2; ++i) {
        const int c = tid + 256 * i;            // 512 A chunks
        const int q = c >> 7, row = c & 127;
        int m = m0 + row; if (m >= Meff) m = Meff - 1;   // clamp: dup loads, store-guarded
        gA[i] = A + (size_t)rl[m] * K + q * 8;
        lA[i] = (void*)&As[(size_t)c * 8];
    }
    const unsigned short* gB[NBCH]; void* lB[NBCH];
    #pragma unroll
    for (int i = 0; i < NBCH; ++i) {
        const int c = tid + 256 * i;            // 4*BN B chunks
        const int q = c / BN, n = c % BN;
        gB[i] = Bp + (((size_t)e * (K / 8) + q) * N + n0 + n) * 8;
        lB[i] = (void*)&Bs[(size_t)c * 8];
    }

    f32x4 acc[4][NI];
    #pragma unroll
    for (int mi = 0; mi < 4; ++mi)
        #pragma unroll
        for (int ni = 0; ni < NI; ++ni)
            acc[mi][ni] = (f32x4){0.f, 0.f, 0.f, 0.f};

    const size_t bstep = (size_t)4 * N * 8;     // advance 4 k8-slices per step
    for (int ks = 0; ks < K / 32; ++ks) {
        __syncthreads();
        gload_lds16(gA[0], lA[0]);
        gload_lds16(gA[1], lA[1]);
        #pragma unroll
        for (int i = 0; i < NBCH; ++i) gload_lds16(gB[i], lB[i]);
        gA[0] += 32; gA[1] += 32;
        #pragma unroll
        for (int i = 0; i < NBCH; ++i) gB[i] += bstep;
        __syncthreads();                         // drains vmcnt before ds_read

        bf16x8 af[4], bfr[NI];
        #pragma unroll
        for (int mi = 0; mi < 4; ++mi)
            af[mi] = *(const bf16x8*)&As[((size_t)quad * 128 + wm + mi * 16 + l16) * 8];
        #pragma unroll
        for (int ni = 0; ni < NI; ++ni)
            bfr[ni] = *(const bf16x8*)&Bs[((size_t)quad * BN + wn + ni * 16 + l16) * 8];
        #pragma unroll
        for (int mi = 0; mi < 4; ++mi)
            #pragma unroll
            for (int ni = 0; ni < NI; ++ni)
                acc[mi][ni] = __builtin_amdgcn_mfma_f32_16x16x32_bf16(
                    af[mi], bfr[ni], acc[mi][ni], 0, 0, 0);
    }

    // epilogue: C/D layout col=l16, row=quad*4+reg (m89/m91 verified)
    #pragma unroll
    for (int mi = 0; mi < 4; ++mi) {
        const int rbase = wm + mi * 16 + quad * 4;
        #pragma unroll
        for (int r = 0; r < 4; ++r) {
            const int m = m0 + rbase + r;
            if (m >= Meff) continue;
            const int gr = rl[m];
            #pragma unroll
            for (int ni = 0; ni < NI; ++ni) {
                const int col = n0 + wn + ni * 16 + l16;
                float vv = acc[mi][ni][r] + bias[(size_t)e * N + col];
                if (BF16OUT) {
                    vv = fmaxf(vv, 0.f);
                    ((unsigned short*)Cout)[(size_t)gr * N + col] = f2bf(vv);
                } else {
                    vv += resid[(size_t)gr * N + col];
                    ((float*)Cout)[(size_t)gr * N + col] = vv;
                }
            }
        }
    }
}

// ---------------------------------------------------------------------------
extern "C" void kernel_launch(void* const* d_in, const int* in_sizes, int n_in,
                              void* d_out, int out_size, void* d_ws, size_t ws_size,
                              hipStream_t stream)
{
    (void)in_sizes; (void)n_in; (void)out_size; (void)ws_size;
    const float* x      = (const float*)d_in[0];
    const float* ln1_g  = (const float*)d_in[1];
    const float* ln1_b  = (const float*)d_in[2];
    const float* ln2_g  = (const float*)d_in[3];
    const float* ln2_b  = (const float*)d_in[4];
    const float* wq     = (const float*)d_in[5];
    const float* bq     = (const float*)d_in[6];
    const float* wk     = (const float*)d_in[7];
    const float* bk     = (const float*)d_in[8];
    const float* wv     = (const float*)d_in[9];
    const float* bv     = (const float*)d_in[10];
    const float* wo     = (const float*)d_in[11];
    const float* bo     = (const float*)d_in[12];
    const float* gate_w = (const float*)d_in[13];
    const float* gate_b = (const float*)d_in[14];
    const float* w1     = (const float*)d_in[15];
    const float* b1     = (const float*)d_in[16];
    const float* w2     = (const float*)d_in[17];
    const float* b2     = (const float*)d_in[18];
    float* out = (float*)d_out;

    // workspace (120.2 MiB; R1 used 128.2 MiB successfully):
    //  [0,16)   k          --\
    //  [16,32)  v             \ all four freed before pack_w1 -> reused as
    //  [32,48)  hn, then o    / wpack (64 MiB, w1 packed then w2 packed)
    //  [48,64)  hn2 fp32   --/
    //  [64,80)  q, then x2 (lives until GEMM2)
    //  [80,88)  hn2 bf16
    //  [88,120) mid bf16
    //  [120,..) tok lists + counts
    char* W8 = (char*)d_ws;
    float*          kbuf  = (float*)(W8);
    float*          vbuf  = (float*)(W8 + 16 * MiB);
    float*          hnbuf = (float*)(W8 + 32 * MiB);
    float*          hn2f  = (float*)(W8 + 48 * MiB);
    unsigned short* wpack = (unsigned short*)(W8);
    float*          qbuf  = (float*)(W8 + 64 * MiB);
    unsigned short* hn2bf = (unsigned short*)(W8 + 80 * MiB);
    unsigned short* mid   = (unsigned short*)(W8 + 88 * MiB);
    int*            tok   = (int*)(W8 + 120 * MiB);
    int*            cnts  = (int*)(W8 + 120 * MiB + (size_t)NE * NT * 4);

    // 1. hn = LN1(x)
    ln_kernel<false><<<NT, 256, 0, stream>>>(x, ln1_g, ln1_b, hnbuf, nullptr);

    // 2. q,k,v = hn @ {wq,wk,wv} + {bq,bk,bv}   (fused over z)
    {
        dim3 g(NHID / 128, NT / 128, 3);
        gemm_kernel<128, false, true><<<g, 256, 0, stream>>>(
            hnbuf, wq, wk, wv, bq, bk, bv, nullptr,
            qbuf, kbuf, vbuf, NT, NHID, NHID);
    }

    // 3. o = attention(q,k,v) -> hnbuf
    {
        dim3 g(NS / 64, NHEAD, NB);
        attn_kernel<<<g, 256, 0, stream>>>(qbuf, kbuf, vbuf, hnbuf);
    }

    // 4. x2 = x + o @ wo + bo -> qbuf
    {
        dim3 g(NHID / 128, NT / 128, 1);
        gemm_kernel<128, true, false><<<g, 256, 0, stream>>>(
            hnbuf, wo, nullptr, nullptr, bo, nullptr, nullptr, x,
            qbuf, nullptr, nullptr, NT, NHID, NHID);
    }

    // 5. hn2 = LN2(x2) -> fp32 (gate) + bf16 (expert GEMM A)
    ln_kernel<true><<<NT, 256, 0, stream>>>(qbuf, ln2_g, ln2_b, hn2f, hn2bf);

    // 6. top-1 routing (fp32; precision-critical)
    hipMemsetAsync(cnts, 0, NE * sizeof(int), stream);
    gate_kernel<<<NT, 64, 0, stream>>>(hn2f, gate_w, gate_b, cnts, tok);

    // 7. pack w1 -> bf16 MFMA-B layout (overwrites k/v/hn/hn2f; all dead)
    {
        dim3 g(NF / 256, NHID / 8, NE);
        pack_w<<<g, 256, 0, stream>>>(w1, wpack, NHID, NF);
    }
    // 8. mid = relu(gather(hn2bf) @ w1[e] + b1[e])  (bf16 out)
    {
        dim3 g(NF / 128, NT / 128, NE);
        moe_mfma<128, true><<<g, 256, 0, stream>>>(
            hn2bf, wpack, b1, nullptr, mid, NF, NHID, tok, cnts);
    }
    // 9. pack w2 (overwrites w1 pack; GEMM1 done)
    {
        dim3 g(NHID / 256, NF / 8, NE);
        pack_w<<<g, 256, 0, stream>>>(w2, wpack, NF, NHID);
    }
    // 10. out = x2 + gather(mid) @ w2[e] + b2[e]  (fp32, BN=64 for occupancy)
    {
        dim3 g(NHID / 64, NT / 128, NE);
        moe_mfma<64, false><<<g, 256, 0, stream>>>(
            mid, wpack, b2, qbuf, out, NHID, NF, tok, cnts);
    }
}

// Round 3
// 1268.977 us; speedup vs baseline: 1.7473x; 1.2395x over previous
//
#include <hip/hip_runtime.h>
#include <math.h>

// ---------------------------------------------------------------------------
// TransformerBlock: LN -> QKV -> MHA -> Wo(+resid) -> LN -> top1-MoE(+resid)
// R3: pre-gate GEMMs (QKV, Wo) in bf16x3 split-precision MFMA (hi/lo planes,
// 3 passes hh+hl+lh -> ~2^-18 relative error, argmax-routing-safe margin).
// Attention fp32 with conflict-free padded-P PV loop. MoE unchanged (R2).
// ---------------------------------------------------------------------------

constexpr int NB = 4, NS = 1024, NHID = 1024, NHEAD = 16, HD = 64, NE = 8, NF = 4096;
constexpr int NT = NB * NS;          // 4096 tokens
constexpr float LN_EPS = 1e-5f;
constexpr size_t MiB = 1048576;

using bf16x8 = __attribute__((ext_vector_type(8))) short;
using f32x4  = __attribute__((ext_vector_type(4))) float;

__device__ __forceinline__ unsigned short f2bf(float x) {
    unsigned u = __float_as_uint(x);
    return (unsigned short)((u + 0x7fffu + ((u >> 16) & 1u)) >> 16);   // RNE
}
__device__ __forceinline__ float bf2f(unsigned short h) {
    return __uint_as_float((unsigned)h << 16);
}

__device__ __forceinline__ void gload_lds16(const void* g, void* l) {
    __builtin_amdgcn_global_load_lds(
        (const __attribute__((address_space(1))) void*)g,
        (__attribute__((address_space(3))) void*)l, 16, 0, 0);
}

// ---------------- LayerNorm ------------------------------------------------
// MODE 0: write hi+lo bf16 planes only (feeds bf16x3 GEMM)
// MODE 1: write fp32 (gate) + hi bf16 plane (feeds 1-pass MoE GEMM)
template<int MODE>
__global__ __launch_bounds__(256)
void ln_kernel(const float* __restrict__ x, const float* __restrict__ g,
               const float* __restrict__ b, float* __restrict__ y,
               unsigned short* __restrict__ yh, unsigned short* __restrict__ yl)
{
    const int t = blockIdx.x, tid = threadIdx.x;
    const float4 xv = ((const float4*)(x + (size_t)t * NHID))[tid];
    float s  = xv.x + xv.y + xv.z + xv.w;
    float sq = xv.x*xv.x + xv.y*xv.y + xv.z*xv.z + xv.w*xv.w;
    for (int off = 32; off > 0; off >>= 1) {
        s  += __shfl_down(s, off);
        sq += __shfl_down(sq, off);
    }
    __shared__ float ws_[4], wsq_[4], stats[2];
    const int wid = tid >> 6, lane = tid & 63;
    if (lane == 0) { ws_[wid] = s; wsq_[wid] = sq; }
    __syncthreads();
    if (tid == 0) {
        const float ts = ws_[0] + ws_[1] + ws_[2] + ws_[3];
        const float tq = wsq_[0] + wsq_[1] + wsq_[2] + wsq_[3];
        const float mu = ts * (1.0f / NHID);
        const float var = tq * (1.0f / NHID) - mu * mu;
        stats[0] = mu; stats[1] = rsqrtf(var + LN_EPS);
    }
    __syncthreads();
    const float mu = stats[0], rs = stats[1];
    const float4 gv = ((const float4*)g)[tid];
    const float4 bv = ((const float4*)b)[tid];
    float ov[4];
    ov[0] = (xv.x - mu) * rs * gv.x + bv.x;
    ov[1] = (xv.y - mu) * rs * gv.y + bv.y;
    ov[2] = (xv.z - mu) * rs * gv.z + bv.z;
    ov[3] = (xv.w - mu) * rs * gv.w + bv.w;
    if (MODE == 1) {
        float4 o4; o4.x = ov[0]; o4.y = ov[1]; o4.z = ov[2]; o4.w = ov[3];
        ((float4*)(y + (size_t)t * NHID))[tid] = o4;
    }
    unsigned long long ph = 0, pl = 0;
    #pragma unroll
    for (int j = 0; j < 4; ++j) {
        const unsigned short h = f2bf(ov[j]);
        ph |= (unsigned long long)h << (16 * j);
        if (MODE == 0) pl |= (unsigned long long)f2bf(ov[j] - bf2f(h)) << (16 * j);
    }
    ((unsigned long long*)(yh + (size_t)t * NHID))[tid] = ph;
    if (MODE == 0)
        ((unsigned long long*)(yl + (size_t)t * NHID))[tid] = pl;
}

// ---------------- Pack weight fp32 [K][N] -> bf16 [2][K/8][N][8] (hi,lo) ---
__global__ __launch_bounds__(256)
void pack_whl(const float* __restrict__ w, unsigned short* __restrict__ out,
              int K, int N)
{
    const int k8 = blockIdx.y;
    const int col = blockIdx.x * 256 + threadIdx.x;
    const float* src = w + (size_t)k8 * 8 * N + col;
    unsigned short th[8] __attribute__((aligned(16)));
    unsigned short tl[8] __attribute__((aligned(16)));
    #pragma unroll
    for (int j = 0; j < 8; ++j) {
        const float f = src[(size_t)j * N];
        th[j] = f2bf(f);
        tl[j] = f2bf(f - bf2f(th[j]));
    }
    const size_t plane = (size_t)(K / 8) * N * 8;
    const size_t o = ((size_t)k8 * N + col) * 8;
    *(f32x4*)(out + o)         = *(const f32x4*)th;
    *(f32x4*)(out + plane + o) = *(const f32x4*)tl;
}

// ---------------- Pack weight fp32 [E][K][N] -> bf16 [E][K/8][N][8] (hi) ---
__global__ __launch_bounds__(256)
void pack_w(const float* __restrict__ w, unsigned short* __restrict__ out,
            int K, int N)
{
    const int e = blockIdx.z, k8 = blockIdx.y;
    const int col = blockIdx.x * 256 + threadIdx.x;
    const float* src = w + ((size_t)e * K + (size_t)k8 * 8) * N + col;
    unsigned short tmp[8] __attribute__((aligned(16)));
    #pragma unroll
    for (int j = 0; j < 8; ++j) tmp[j] = f2bf(src[(size_t)j * N]);
    *(f32x4*)(out + (((size_t)e * (K / 8) + k8) * N + col) * 8) = *(const f32x4*)tmp;
}

// ---------------- bf16x3 MFMA GEMM: C = A @ W + bias (+resid) --------------
// A as hi/lo bf16 planes [M][K]; W packed [2][K/8][N][8] (hi,lo).
// BM=BN=128, BK=32, 256 thr (4 waves, 2x2). 3 MFMA passes: hh, hl, lh.
// QKV3: blockIdx.z selects weight z (stride 2*(K/8)*N*8), bias z, C + z*NT*N.
template<bool QKV3, bool RESID>
__global__ __launch_bounds__(256, 2)
void gemm3(const unsigned short* __restrict__ Ah, const unsigned short* __restrict__ Al,
           const unsigned short* __restrict__ Bp,
           const float* __restrict__ b0, const float* __restrict__ b1,
           const float* __restrict__ b2,
           const float* __restrict__ resid, float* __restrict__ C,
           int N, int K)
{
    __shared__ __attribute__((aligned(16))) unsigned short Ahs[4 * 128 * 8];
    __shared__ __attribute__((aligned(16))) unsigned short Als[4 * 128 * 8];
    __shared__ __attribute__((aligned(16))) unsigned short Bhs[4 * 128 * 8];
    __shared__ __attribute__((aligned(16))) unsigned short Bls[4 * 128 * 8];

    const int z  = QKV3 ? blockIdx.z : 0;
    const int m0 = blockIdx.y * 128;
    const int n0 = blockIdx.x * 128;
    const size_t plane = (size_t)(K / 8) * N * 8;
    const unsigned short* Bh = Bp + (size_t)z * 2 * plane;
    const unsigned short* Bl = Bh + plane;
    const float* bp = QKV3 ? (z == 0 ? b0 : z == 1 ? b1 : b2) : b0;
    float* Cp = C + (QKV3 ? (size_t)z * NT * N : 0);

    const int tid  = threadIdx.x;
    const int lane = tid & 63, wid = tid >> 6;
    const int quad = lane >> 4, l16 = lane & 15;
    const int wm = (wid >> 1) * 64;
    const int wn = (wid & 1) * 64;

    // staging: chunk c = q*128 + idx (16B per chunk), 512 chunks/plane, 2/thread
    const unsigned short *gAh[2], *gAl[2], *gBh[2], *gBl[2];
    void *lAh[2], *lAl[2], *lBh[2], *lBl[2];
    #pragma unroll
    for (int i = 0; i < 2; ++i) {
        const int c = tid + 256 * i;
        const int q = c >> 7, idx = c & 127;
        gAh[i] = Ah + (size_t)(m0 + idx) * K + q * 8;
        gAl[i] = Al + (size_t)(m0 + idx) * K + q * 8;
        gBh[i] = Bh + ((size_t)q * N + n0 + idx) * 8;
        gBl[i] = Bl + ((size_t)q * N + n0 + idx) * 8;
        lAh[i] = (void*)&Ahs[(size_t)c * 8];
        lAl[i] = (void*)&Als[(size_t)c * 8];
        lBh[i] = (void*)&Bhs[(size_t)c * 8];
        lBl[i] = (void*)&Bls[(size_t)c * 8];
    }

    f32x4 acc[4][4];
    #pragma unroll
    for (int mi = 0; mi < 4; ++mi)
        #pragma unroll
        for (int ni = 0; ni < 4; ++ni)
            acc[mi][ni] = (f32x4){0.f, 0.f, 0.f, 0.f};

    const size_t bstep = (size_t)4 * N * 8;
    for (int ks = 0; ks < K / 32; ++ks) {
        __syncthreads();
        #pragma unroll
        for (int i = 0; i < 2; ++i) {
            gload_lds16(gAh[i], lAh[i]);
            gload_lds16(gAl[i], lAl[i]);
            gload_lds16(gBh[i], lBh[i]);
            gload_lds16(gBl[i], lBl[i]);
            gAh[i] += 32; gAl[i] += 32; gBh[i] += bstep; gBl[i] += bstep;
        }
        __syncthreads();

        bf16x8 ah[4], al[4], bh[4], bl[4];
        #pragma unroll
        for (int mi = 0; mi < 4; ++mi) {
            ah[mi] = *(const bf16x8*)&Ahs[((size_t)quad * 128 + wm + mi * 16 + l16) * 8];
            al[mi] = *(const bf16x8*)&Als[((size_t)quad * 128 + wm + mi * 16 + l16) * 8];
        }
        #pragma unroll
        for (int ni = 0; ni < 4; ++ni) {
            bh[ni] = *(const bf16x8*)&Bhs[((size_t)quad * 128 + wn + ni * 16 + l16) * 8];
            bl[ni] = *(const bf16x8*)&Bls[((size_t)quad * 128 + wn + ni * 16 + l16) * 8];
        }
        #pragma unroll
        for (int mi = 0; mi < 4; ++mi)
            #pragma unroll
            for (int ni = 0; ni < 4; ++ni) {
                acc[mi][ni] = __builtin_amdgcn_mfma_f32_16x16x32_bf16(
                    ah[mi], bh[ni], acc[mi][ni], 0, 0, 0);
                acc[mi][ni] = __builtin_amdgcn_mfma_f32_16x16x32_bf16(
                    ah[mi], bl[ni], acc[mi][ni], 0, 0, 0);
                acc[mi][ni] = __builtin_amdgcn_mfma_f32_16x16x32_bf16(
                    al[mi], bh[ni], acc[mi][ni], 0, 0, 0);
            }
    }

    // epilogue: C/D layout col=l16, row=quad*4+reg
    #pragma unroll
    for (int mi = 0; mi < 4; ++mi) {
        const int rbase = wm + mi * 16 + quad * 4;
        #pragma unroll
        for (int r = 0; r < 4; ++r) {
            const size_t gm = m0 + rbase + r;
            #pragma unroll
            for (int ni = 0; ni < 4; ++ni) {
                const int col = n0 + wn + ni * 16 + l16;
                float vv = acc[mi][ni][r] + bp[col];
                if (RESID) vv += resid[gm * N + col];
                Cp[gm * N + col] = vv;
            }
        }
    }
}

// ---------------- Flash-style fp32 attention (padded-P PV) ------------------
__device__ __forceinline__ int kvslot(int j, int s) {
    return s ^ (j >> 2) ^ ((j & 3) << 2);   // bijective in s for fixed j
}

__global__ __launch_bounds__(256)
void attn_kernel(const float* __restrict__ q, const float* __restrict__ k,
                 const float* __restrict__ v,
                 unsigned short* __restrict__ oh, unsigned short* __restrict__ ol)
{
    __shared__ float Qs[64][68];     // pad 68: 2-way max on row-strided reads
    __shared__ float Ksw[64 * 64];   // swizzled K
    __shared__ float Vsw[64 * 64];   // swizzled V
    __shared__ float Ps[64][68];     // P, padded rows (float4-aligned: 68*4=272=17*16)

    const int qt = blockIdx.x, h = blockIdx.y, b = blockIdx.z;
    const int tid = threadIdx.x;
    const int tr = tid >> 4, tc = tid & 15;
    const size_t base = ((size_t)b * NS) * NHID + (size_t)h * HD;

    for (int c = tid; c < 64 * 16; c += 256) {
        const int i = c >> 4, d4 = (c & 15) << 2;
        const float4 qv = *(const float4*)&q[base + (size_t)(qt * 64 + i) * NHID + d4];
        Qs[i][d4 + 0] = qv.x * 0.125f;   // fold 1/sqrt(D)
        Qs[i][d4 + 1] = qv.y * 0.125f;
        Qs[i][d4 + 2] = qv.z * 0.125f;
        Qs[i][d4 + 3] = qv.w * 0.125f;
    }

    float m_run[4], l_run[4], o_acc[4][4];
    #pragma unroll
    for (int i = 0; i < 4; ++i) {
        m_run[i] = -1e30f; l_run[i] = 0.f;
        #pragma unroll
        for (int d = 0; d < 4; ++d) o_acc[i][d] = 0.f;
    }

    for (int kt = 0; kt < NS / 64; ++kt) {
        __syncthreads();   // prev S/PV reads of Ksw/Vsw/Ps done; Q ready (1st iter)
        for (int c = tid; c < 64 * 16; c += 256) {
            const int j = c >> 4, d4 = (c & 15) << 2;
            const int ss = kvslot(j, d4 >> 2);
            const float4 kv = *(const float4*)&k[base + (size_t)(kt * 64 + j) * NHID + d4];
            *(float4*)&Ksw[j * 64 + ss * 4] = kv;
            const float4 vv = *(const float4*)&v[base + (size_t)(kt * 64 + j) * NHID + d4];
            *(float4*)&Vsw[j * 64 + ss * 4] = vv;
        }
        __syncthreads();

        // S tile: rows tr*4+ii, cols tc*4+jj
        float sc[4][4] = {};
        #pragma unroll 2
        for (int d4 = 0; d4 < 64; d4 += 4) {
            float4 qv[4], kv[4];
            #pragma unroll
            for (int ii = 0; ii < 4; ++ii)
                qv[ii] = *(const float4*)&Qs[tr * 4 + ii][d4];
            #pragma unroll
            for (int jj = 0; jj < 4; ++jj) {
                const int j = tc * 4 + jj;
                kv[jj] = *(const float4*)&Ksw[j * 64 + kvslot(j, d4 >> 2) * 4];
            }
            #pragma unroll
            for (int ii = 0; ii < 4; ++ii)
                #pragma unroll
                for (int jj = 0; jj < 4; ++jj)
                    sc[ii][jj] += qv[ii].x * kv[jj].x + qv[ii].y * kv[jj].y
                                + qv[ii].z * kv[jj].z + qv[ii].w * kv[jj].w;
        }

        // online softmax; 16 lanes (same tr) own a row, xor-reduce over tc
        float alpha[4];
        #pragma unroll
        for (int ii = 0; ii < 4; ++ii) {
            float tm = fmaxf(fmaxf(sc[ii][0], sc[ii][1]), fmaxf(sc[ii][2], sc[ii][3]));
            for (int msk = 1; msk < 16; msk <<= 1) tm = fmaxf(tm, __shfl_xor(tm, msk));
            const float newm = fmaxf(m_run[ii], tm);
            alpha[ii] = __expf(m_run[ii] - newm);
            float4 p4;
            p4.x = __expf(sc[ii][0] - newm); p4.y = __expf(sc[ii][1] - newm);
            p4.z = __expf(sc[ii][2] - newm); p4.w = __expf(sc[ii][3] - newm);
            float ps = p4.x + p4.y + p4.z + p4.w;
            for (int msk = 1; msk < 16; msk <<= 1) ps += __shfl_xor(ps, msk);
            l_run[ii] = l_run[ii] * alpha[ii] + ps;
            m_run[ii] = newm;
            *(float4*)&Ps[tr * 4 + ii][tc * 4] = p4;   // own buffer: no pre-sync needed
        }
        __syncthreads();   // P visible to all

        // PV: O[i][4tc..+3] += sum_j P[i][j] * V[j][4tc..+3]; P read as float4
        #pragma unroll
        for (int ii = 0; ii < 4; ++ii)
            #pragma unroll
            for (int dd = 0; dd < 4; ++dd)
                o_acc[ii][dd] *= alpha[ii];
        #pragma unroll 2
        for (int j4 = 0; j4 < 64; j4 += 4) {
            float4 pv4[4], vv4[4];
            #pragma unroll
            for (int ii = 0; ii < 4; ++ii)
                pv4[ii] = *(const float4*)&Ps[tr * 4 + ii][j4];
            #pragma unroll
            for (int jj = 0; jj < 4; ++jj)
                vv4[jj] = *(const float4*)&Vsw[(j4 + jj) * 64 + kvslot(j4 + jj, tc) * 4];
            #pragma unroll
            for (int ii = 0; ii < 4; ++ii) {
                o_acc[ii][0] += pv4[ii].x * vv4[0].x + pv4[ii].y * vv4[1].x
                              + pv4[ii].z * vv4[2].x + pv4[ii].w * vv4[3].x;
                o_acc[ii][1] += pv4[ii].x * vv4[0].y + pv4[ii].y * vv4[1].y
                              + pv4[ii].z * vv4[2].y + pv4[ii].w * vv4[3].y;
                o_acc[ii][2] += pv4[ii].x * vv4[0].z + pv4[ii].y * vv4[1].z
                              + pv4[ii].z * vv4[2].z + pv4[ii].w * vv4[3].z;
                o_acc[ii][3] += pv4[ii].x * vv4[0].w + pv4[ii].y * vv4[1].w
                              + pv4[ii].z * vv4[2].w + pv4[ii].w * vv4[3].w;
            }
        }
    }

    // epilogue: normalize + split to hi/lo bf16 planes (feeds bf16x3 Wo GEMM)
    #pragma unroll
    for (int ii = 0; ii < 4; ++ii) {
        const float inv = 1.f / l_run[ii];
        const size_t o = base + (size_t)(qt * 64 + tr * 4 + ii) * NHID + tc * 4;
        unsigned long long ph = 0, pl = 0;
        #pragma unroll
        for (int dd = 0; dd < 4; ++dd) {
            const float vv = o_acc[ii][dd] * inv;
            const unsigned short hh = f2bf(vv);
            ph |= (unsigned long long)hh << (16 * dd);
            pl |= (unsigned long long)f2bf(vv - bf2f(hh)) << (16 * dd);
        }
        *(unsigned long long*)&oh[o] = ph;
        *(unsigned long long*)&ol[o] = pl;
    }
}

// ---------------- Gate: fp32 logits, argmax (first-max), token scatter ------
__global__ __launch_bounds__(64)
void gate_kernel(const float* __restrict__ hn2, const float* __restrict__ gw,
                 const float* __restrict__ gb, int* __restrict__ counts,
                 int* __restrict__ tok)
{
    const int t = blockIdx.x, lane = threadIdx.x;
    const float* row = hn2 + (size_t)t * NHID;
    float acc[NE] = {};
    for (int hh = lane; hh < NHID; hh += 64) {
        const float xv = row[hh];
        const float4 g0 = ((const float4*)(gw + (size_t)hh * NE))[0];
        const float4 g1 = ((const float4*)(gw + (size_t)hh * NE))[1];
        acc[0] += xv * g0.x; acc[1] += xv * g0.y; acc[2] += xv * g0.z; acc[3] += xv * g0.w;
        acc[4] += xv * g1.x; acc[5] += xv * g1.y; acc[6] += xv * g1.z; acc[7] += xv * g1.w;
    }
    #pragma unroll
    for (int e = 0; e < NE; ++e)
        for (int off = 32; off > 0; off >>= 1)
            acc[e] += __shfl_down(acc[e], off);
    if (lane == 0) {
        float best = -1e30f; int bi = 0;
        #pragma unroll
        for (int e = 0; e < NE; ++e) {
            const float lv = acc[e] + gb[e];
            if (lv > best) { best = lv; bi = e; }   // strict >: first-max (jnp.argmax)
        }
        const int pos = atomicAdd(&counts[bi], 1);
        tok[(size_t)bi * NT + pos] = t;
    }
}

// ---------------- MoE expert GEMM, 1-pass bf16 MFMA (unchanged from R2) -----
template<int BN, bool BF16OUT>
__global__ __launch_bounds__(256, 2)
void moe_mfma(const unsigned short* __restrict__ A,   // bf16 [NT][K]
              const unsigned short* __restrict__ Bp,  // bf16 packed [E][K/8][N][8]
              const float* __restrict__ bias,         // [E][N]
              const float* __restrict__ resid,        // [NT][N] or null
              void* __restrict__ Cout,                // bf16 or fp32 [NT][N]
              int N, int K,
              const int* __restrict__ rows, const int* __restrict__ counts)
{
    constexpr int NI = BN / 32;
    constexpr int NBCH = (4 * BN) / 256;
    __shared__ __attribute__((aligned(16))) unsigned short As[4 * 128 * 8];
    __shared__ __attribute__((aligned(16))) unsigned short Bs[4 * BN * 8];

    const int e = blockIdx.z;
    const int Meff = counts[e];
    const int m0 = blockIdx.y * 128;
    if (m0 >= Meff) return;
    const int n0 = blockIdx.x * BN;
    const int* rl = rows + (size_t)e * NT;

    const int tid  = threadIdx.x;
    const int lane = tid & 63, wid = tid >> 6;
    const int quad = lane >> 4, l16 = lane & 15;
    const int wm = (wid >> 1) * 64;
    const int wn = (wid & 1) * (BN / 2);

    const unsigned short* gA[2]; void* lA[2];
    #pragma unroll
    for (int i = 0; i < 2; ++i) {
        const int c = tid + 256 * i;
        const int q = c >> 7, row = c & 127;
        int m = m0 + row; if (m >= Meff) m = Meff - 1;
        gA[i] = A + (size_t)rl[m] * K + q * 8;
        lA[i] = (void*)&As[(size_t)c * 8];
    }
    const unsigned short* gB[NBCH]; void* lB[NBCH];
    #pragma unroll
    for (int i = 0; i < NBCH; ++i) {
        const int c = tid + 256 * i;
        const int q = c / BN, n = c % BN;
        gB[i] = Bp + (((size_t)e * (K / 8) + q) * N + n0 + n) * 8;
        lB[i] = (void*)&Bs[(size_t)c * 8];
    }

    f32x4 acc[4][NI];
    #pragma unroll
    for (int mi = 0; mi < 4; ++mi)
        #pragma unroll
        for (int ni = 0; ni < NI; ++ni)
            acc[mi][ni] = (f32x4){0.f, 0.f, 0.f, 0.f};

    const size_t bstep = (size_t)4 * N * 8;
    for (int ks = 0; ks < K / 32; ++ks) {
        __syncthreads();
        gload_lds16(gA[0], lA[0]);
        gload_lds16(gA[1], lA[1]);
        #pragma unroll
        for (int i = 0; i < NBCH; ++i) gload_lds16(gB[i], lB[i]);
        gA[0] += 32; gA[1] += 32;
        #pragma unroll
        for (int i = 0; i < NBCH; ++i) gB[i] += bstep;
        __syncthreads();

        bf16x8 af[4], bfr[NI];
        #pragma unroll
        for (int mi = 0; mi < 4; ++mi)
            af[mi] = *(const bf16x8*)&As[((size_t)quad * 128 + wm + mi * 16 + l16) * 8];
        #pragma unroll
        for (int ni = 0; ni < NI; ++ni)
            bfr[ni] = *(const bf16x8*)&Bs[((size_t)quad * BN + wn + ni * 16 + l16) * 8];
        #pragma unroll
        for (int mi = 0; mi < 4; ++mi)
            #pragma unroll
            for (int ni = 0; ni < NI; ++ni)
                acc[mi][ni] = __builtin_amdgcn_mfma_f32_16x16x32_bf16(
                    af[mi], bfr[ni], acc[mi][ni], 0, 0, 0);
    }

    #pragma unroll
    for (int mi = 0; mi < 4; ++mi) {
        const int rbase = wm + mi * 16 + quad * 4;
        #pragma unroll
        for (int r = 0; r < 4; ++r) {
            const int m = m0 + rbase + r;
            if (m >= Meff) continue;
            const int gr = rl[m];
            #pragma unroll
            for (int ni = 0; ni < NI; ++ni) {
                const int col = n0 + wn + ni * 16 + l16;
                float vv = acc[mi][ni][r] + bias[(size_t)e * N + col];
                if (BF16OUT) {
                    vv = fmaxf(vv, 0.f);
                    ((unsigned short*)Cout)[(size_t)gr * N + col] = f2bf(vv);
                } else {
                    vv += resid[(size_t)gr * N + col];
                    ((float*)Cout)[(size_t)gr * N + col] = vv;
                }
            }
        }
    }
}

// ---------------------------------------------------------------------------
extern "C" void kernel_launch(void* const* d_in, const int* in_sizes, int n_in,
                              void* d_out, int out_size, void* d_ws, size_t ws_size,
                              hipStream_t stream)
{
    (void)in_sizes; (void)n_in; (void)out_size; (void)ws_size;
    const float* x      = (const float*)d_in[0];
    const float* ln1_g  = (const float*)d_in[1];
    const float* ln1_b  = (const float*)d_in[2];
    const float* ln2_g  = (const float*)d_in[3];
    const float* ln2_b  = (const float*)d_in[4];
    const float* wq     = (const float*)d_in[5];
    const float* bq     = (const float*)d_in[6];
    const float* wk     = (const float*)d_in[7];
    const float* bk     = (const float*)d_in[8];
    const float* wv     = (const float*)d_in[9];
    const float* bv     = (const float*)d_in[10];
    const float* wo     = (const float*)d_in[11];
    const float* bo     = (const float*)d_in[12];
    const float* gate_w = (const float*)d_in[13];
    const float* gate_b = (const float*)d_in[14];
    const float* w1     = (const float*)d_in[15];
    const float* b1     = (const float*)d_in[16];
    const float* w2     = (const float*)d_in[17];
    const float* b2     = (const float*)d_in[18];
    float* out = (float*)d_out;

    // workspace layout (128 MiB total; R1 proved 128.13 MiB ok):
    //  0-16   q        -> (after Wo) MoE wpack [0,64)
    //  16-32  k
    //  32-48  v
    //  48-56  hnh      -> (after QKV) oh
    //  56-64  hnl      -> ol
    //  64-76  qkv weight packs (hi+lo, 4 MiB each) -> (after Wo) hn2bf 64-72
    //  72-76  (dead wv pack) -> tok (128 KB) + cnts
    //  76-80  wo pack
    //  80-96  x2 (alive to end)
    //  96-112 hn2f     -> (after gate) mid low half
    //  96-128 mid bf16 [NT][NF]
    char* W8 = (char*)d_ws;
    float*          qbuf   = (float*)(W8);
    float*          kbuf   = (float*)(W8 + 16 * MiB);
    float*          vbuf   = (float*)(W8 + 32 * MiB);
    unsigned short* hnh    = (unsigned short*)(W8 + 48 * MiB);
    unsigned short* hnl    = (unsigned short*)(W8 + 56 * MiB);
    unsigned short* ohb    = (unsigned short*)(W8 + 48 * MiB);
    unsigned short* olb    = (unsigned short*)(W8 + 56 * MiB);
    unsigned short* qkvpk  = (unsigned short*)(W8 + 64 * MiB);   // [3][2][128][1024][8]
    unsigned short* wopk   = (unsigned short*)(W8 + 76 * MiB);
    unsigned short* hn2bf  = (unsigned short*)(W8 + 64 * MiB);
    int*            tok    = (int*)(W8 + 72 * MiB);
    int*            cnts   = (int*)(W8 + 72 * MiB + (size_t)NE * NT * 4);
    float*          x2buf  = (float*)(W8 + 80 * MiB);
    float*          hn2f   = (float*)(W8 + 96 * MiB);
    unsigned short* mid    = (unsigned short*)(W8 + 96 * MiB);
    unsigned short* wpack  = (unsigned short*)(W8);              // MoE, 64 MiB

    const size_t wsz = (size_t)2 * NHID * NHID;   // elems per packed weight (hi+lo)

    // 0. pack QKV + Wo weights -> hi/lo bf16 planes
    {
        dim3 g(NHID / 256, NHID / 8, 1);
        pack_whl<<<g, 256, 0, stream>>>(wq, qkvpk,           NHID, NHID);
        pack_whl<<<g, 256, 0, stream>>>(wk, qkvpk + wsz,     NHID, NHID);
        pack_whl<<<g, 256, 0, stream>>>(wv, qkvpk + 2 * wsz, NHID, NHID);
        pack_whl<<<g, 256, 0, stream>>>(wo, wopk,            NHID, NHID);
    }

    // 1. LN1(x) -> hi/lo planes
    ln_kernel<0><<<NT, 256, 0, stream>>>(x, ln1_g, ln1_b, nullptr, hnh, hnl);

    // 2. q,k,v = hn @ {wq,wk,wv} + bias   (bf16x3 MFMA, fused over z)
    {
        dim3 g(NHID / 128, NT / 128, 3);
        gemm3<true, false><<<g, 256, 0, stream>>>(
            hnh, hnl, qkvpk, bq, bk, bv, nullptr, qbuf, NHID, NHID);
    }

    // 3. o = attention(q,k,v) -> hi/lo planes (overwrites hnh/hnl)
    {
        dim3 g(NS / 64, NHEAD, NB);
        attn_kernel<<<g, 256, 0, stream>>>(qbuf, kbuf, vbuf, ohb, olb);
    }

    // 4. x2 = x + o @ wo + bo   (bf16x3 MFMA)
    {
        dim3 g(NHID / 128, NT / 128, 1);
        gemm3<false, true><<<g, 256, 0, stream>>>(
            ohb, olb, wopk, bo, nullptr, nullptr, x, x2buf, NHID, NHID);
    }

    // 5. hn2 = LN2(x2) -> fp32 (gate) + bf16 hi (MoE A)
    ln_kernel<1><<<NT, 256, 0, stream>>>(x2buf, ln2_g, ln2_b, hn2f, hn2bf, nullptr);

    // 6. top-1 routing (fp32)
    hipMemsetAsync(cnts, 0, NE * sizeof(int), stream);
    gate_kernel<<<NT, 64, 0, stream>>>(hn2f, gate_w, gate_b, cnts, tok);

    // 7. pack w1 (hi only) -> wpack (overwrites q/k/v/oh/ol; all dead)
    {
        dim3 g(NF / 256, NHID / 8, NE);
        pack_w<<<g, 256, 0, stream>>>(w1, wpack, NHID, NF);
    }
    // 8. mid = relu(gather(hn2bf) @ w1[e] + b1[e])  (bf16 out; overlays hn2f)
    {
        dim3 g(NF / 128, NT / 128, NE);
        moe_mfma<128, true><<<g, 256, 0, stream>>>(
            hn2bf, wpack, b1, nullptr, mid, NF, NHID, tok, cnts);
    }
    // 9. pack w2 (GEMM1 done with w1 pack)
    {
        dim3 g(NHID / 256, NF / 8, NE);
        pack_w<<<g, 256, 0, stream>>>(w2, wpack, NF, NHID);
    }
    // 10. out = x2 + gather(mid) @ w2[e] + b2[e]
    {
        dim3 g(NHID / 64, NT / 128, NE);
        moe_mfma<64, false><<<g, 256, 0, stream>>>(
            mid, wpack, b2, x2buf, out, NHID, NF, tok, cnts);
    }
}